// Round 1
// baseline (875.261 us; speedup 1.0000x reference)
//
#include <hip/hip_runtime.h>
#include <hip/hip_bf16.h>

// Problem constants
#define NDIM 256   // outer n
#define QDIM 256   // q/k sequence
#define CDIM 128   // channels
#define HH 4       // heads
#define DD 32      // head dim
#define RROWS (NDIM * QDIM)  // 65536 flattened rows

// ---------- bf16 helpers (raw ushort storage, fp32 compute) ----------
__device__ __forceinline__ float bf2f(unsigned short u) {
    unsigned int x = ((unsigned int)u) << 16;
    return __uint_as_float(x);
}
__device__ __forceinline__ unsigned short f2bf(float f) {
    unsigned int x = __float_as_uint(f);
    unsigned int lsb = (x >> 16) & 1u;
    x += 0x7fffu + lsb;   // round-to-nearest-even
    return (unsigned short)(x >> 16);
}

// =====================================================================
// Kernel 1: projections.  blockIdx.y selects which projection:
//   0: q = (q_x @ Wq) * (1/sqrt(32)) -> q_ws [n][h][q][32] bf16
//   1: k = kv_x @ Wk                 -> k_ws [n][h][k][32] bf16
//   2: v = kv_x @ Wv                 -> v_ws [n][h][k][32] bf16
//   3: g = sigmoid(q_x @ Wg)         -> g_ws [n][q][128]   bf16
// 64 rows per block, full 128x128 W in LDS, X staged transposed.
// =====================================================================
__global__ __launch_bounds__(256, 1) void proj_kernel(
    const float* __restrict__ qx, const float* __restrict__ kvx,
    const float* __restrict__ Wq, const float* __restrict__ Wk,
    const float* __restrict__ Wv, const float* __restrict__ Wg,
    unsigned short* __restrict__ q_ws, unsigned short* __restrict__ k_ws,
    unsigned short* __restrict__ v_ws, unsigned short* __restrict__ g_ws)
{
    __shared__ float Wl[128 * 128];   // [k][c]  64 KB
    __shared__ float Xl[128 * 68];    // [k][row] padded, 34 KB

    const int tid = threadIdx.x;
    const int p = blockIdx.y;
    const float* __restrict__ X = (p == 0 || p == 3) ? qx : kvx;
    const float* __restrict__ W = (p == 0) ? Wq : (p == 1) ? Wk : (p == 2) ? Wv : Wg;

    // load W (row-major [k][c])
    for (int i = tid; i < 128 * 128 / 4; i += 256) {
        ((float4*)Wl)[i] = ((const float4*)W)[i];
    }
    // stage 64 rows of X, transposed into Xl[k][row]
    const int r0 = blockIdx.x * 64;
    for (int idx = tid; idx < 64 * 32; idx += 256) {
        int row = idx >> 5;
        int c4 = idx & 31;
        float4 xv = ((const float4*)(X + (size_t)(r0 + row) * 128))[c4];
        Xl[(c4 * 4 + 0) * 68 + row] = xv.x;
        Xl[(c4 * 4 + 1) * 68 + row] = xv.y;
        Xl[(c4 * 4 + 2) * 68 + row] = xv.z;
        Xl[(c4 * 4 + 3) * 68 + row] = xv.w;
    }
    __syncthreads();

    const int ti = tid & 15;   // col group: cols 8*ti .. 8*ti+7
    const int tj = tid >> 4;   // row group: rows 4*tj .. 4*tj+3

    float acc[4][8];
#pragma unroll
    for (int i = 0; i < 4; ++i)
#pragma unroll
        for (int j = 0; j < 8; ++j) acc[i][j] = 0.f;

    for (int k = 0; k < 128; ++k) {
        float4 xv = *(const float4*)&Xl[k * 68 + 4 * tj];
        float4 w0 = *(const float4*)&Wl[k * 128 + 8 * ti];
        float4 w1 = *(const float4*)&Wl[k * 128 + 8 * ti + 4];
        float xs[4] = {xv.x, xv.y, xv.z, xv.w};
        float ws[8] = {w0.x, w0.y, w0.z, w0.w, w1.x, w1.y, w1.z, w1.w};
#pragma unroll
        for (int i = 0; i < 4; ++i)
#pragma unroll
            for (int j = 0; j < 8; ++j) acc[i][j] = fmaf(xs[i], ws[j], acc[i][j]);
    }

    // epilogue
#pragma unroll
    for (int i = 0; i < 4; ++i) {
        int r = r0 + 4 * tj + i;
        int n = r >> 8;
        int si = r & 255;   // q or k index within n
#pragma unroll
        for (int j = 0; j < 8; ++j) {
            int c = 8 * ti + j;
            float v = acc[i][j];
            if (p == 0) {
                v *= 0.17677669529663687f;  // 1/sqrt(32)
                int h = c >> 5, d = c & 31;
                q_ws[((size_t)(n * HH + h) * QDIM + si) * DD + d] = f2bf(v);
            } else if (p == 1) {
                int h = c >> 5, d = c & 31;
                k_ws[((size_t)(n * HH + h) * QDIM + si) * DD + d] = f2bf(v);
            } else if (p == 2) {
                int h = c >> 5, d = c & 31;
                v_ws[((size_t)(n * HH + h) * QDIM + si) * DD + d] = f2bf(v);
            } else {
                float s = 1.0f / (1.0f + __expf(-v));
                g_ws[(size_t)r * 128 + c] = f2bf(s);
            }
        }
    }
}

// =====================================================================
// Kernel 2: attention per (query-chunk qc, n, h). 64 queries per block.
// S^T stored [ki][qi] in LDS; softmax over ki per row; O = P V; gated.
// =====================================================================
__global__ __launch_bounds__(256, 1) void attn_kernel(
    const unsigned short* __restrict__ q_ws, const unsigned short* __restrict__ k_ws,
    const unsigned short* __restrict__ v_ws, const unsigned short* __restrict__ g_ws,
    const float* __restrict__ tri, const float* __restrict__ mb,
    unsigned short* __restrict__ o_ws)
{
    __shared__ float ql[32 * 68];    // qT [d][qi]   8.5 KB
    __shared__ float kl[32 * 260];   // kT [d][ki]  32.5 KB
    __shared__ float vl[256 * 32];   // v  [ki][d]  32 KB
    __shared__ float st[256 * 68];   // S^T [ki][qi] 68 KB
    __shared__ float redm[256];
    __shared__ float reds[256];
    __shared__ float rowinv[64];

    const int tid = threadIdx.x;
    const int qc = blockIdx.x;   // 0..3
    const int n  = blockIdx.y;
    const int h  = blockIdx.z;
    const size_t base = (size_t)(n * HH + h) * QDIM * DD;

    // stage q (64 x 32, transposed)
    for (int idx = tid; idx < 256; idx += 256) {
        int row = idx >> 2;
        int u = idx & 3;
        uint4 raw = ((const uint4*)(q_ws + base + (size_t)(qc * 64 + row) * 32))[u];
        unsigned int w[4] = {raw.x, raw.y, raw.z, raw.w};
#pragma unroll
        for (int t = 0; t < 4; ++t) {
            ql[(u * 8 + 2 * t + 0) * 68 + row] = bf2f((unsigned short)(w[t] & 0xffff));
            ql[(u * 8 + 2 * t + 1) * 68 + row] = bf2f((unsigned short)(w[t] >> 16));
        }
    }
    // stage k (256 x 32, transposed)
    for (int idx = tid; idx < 1024; idx += 256) {
        int row = idx >> 2;
        int u = idx & 3;
        uint4 raw = ((const uint4*)(k_ws + base + (size_t)row * 32))[u];
        unsigned int w[4] = {raw.x, raw.y, raw.z, raw.w};
#pragma unroll
        for (int t = 0; t < 4; ++t) {
            kl[(u * 8 + 2 * t + 0) * 260 + row] = bf2f((unsigned short)(w[t] & 0xffff));
            kl[(u * 8 + 2 * t + 1) * 260 + row] = bf2f((unsigned short)(w[t] >> 16));
        }
    }
    // stage v (256 x 32, row-major)
    for (int idx = tid; idx < 1024; idx += 256) {
        int row = idx >> 2;
        int u = idx & 3;
        uint4 raw = ((const uint4*)(v_ws + base + (size_t)row * 32))[u];
        unsigned int w[4] = {raw.x, raw.y, raw.z, raw.w};
        float* dst = &vl[row * 32 + u * 8];
#pragma unroll
        for (int t = 0; t < 4; ++t) {
            dst[2 * t + 0] = bf2f((unsigned short)(w[t] & 0xffff));
            dst[2 * t + 1] = bf2f((unsigned short)(w[t] >> 16));
        }
    }
    __syncthreads();

    // ---- Phase 1: S^T = (q k^T + biases)^T ----
    {
        const int ti = tid & 15;   // qi group
        const int tj = tid >> 4;   // ki group (within 64-chunk)
        for (int ch = 0; ch < 4; ++ch) {
            float sacc[4][4];
#pragma unroll
            for (int i = 0; i < 4; ++i) {
                int qg = qc * 64 + 4 * ti + i;
#pragma unroll
                for (int j = 0; j < 4; ++j) {
                    int kg = 64 * ch + 4 * tj + j;
                    sacc[i][j] = mb[n * 256 + kg] +
                                 tri[((size_t)(h * 256 + qg)) * 256 + kg];
                }
            }
            for (int d = 0; d < 32; ++d) {
                float4 qv = *(const float4*)&ql[d * 68 + 4 * ti];
                float4 kv = *(const float4*)&kl[d * 260 + 64 * ch + 4 * tj];
                float qs[4] = {qv.x, qv.y, qv.z, qv.w};
                float ks[4] = {kv.x, kv.y, kv.z, kv.w};
#pragma unroll
                for (int i = 0; i < 4; ++i)
#pragma unroll
                    for (int j = 0; j < 4; ++j)
                        sacc[i][j] = fmaf(qs[i], ks[j], sacc[i][j]);
            }
#pragma unroll
            for (int i = 0; i < 4; ++i)
#pragma unroll
                for (int j = 0; j < 4; ++j)
                    st[(64 * ch + 4 * tj + j) * 68 + (4 * ti + i)] = sacc[i][j];
        }
    }
    __syncthreads();

    // ---- Phase 2: softmax over ki (columns of st are rows of S) ----
    {
        const int row = tid >> 2;   // qi 0..63
        const int part = tid & 3;
        const int k0 = part * 64;
        float m = -1e30f;
        for (int k2 = k0; k2 < k0 + 64; ++k2)
            m = fmaxf(m, st[k2 * 68 + row]);
        redm[row * 4 + part] = m;
        __syncthreads();
        float mr = fmaxf(fmaxf(redm[row * 4], redm[row * 4 + 1]),
                         fmaxf(redm[row * 4 + 2], redm[row * 4 + 3]));
        float s = 0.f;
        for (int k2 = k0; k2 < k0 + 64; ++k2) {
            float e = __expf(st[k2 * 68 + row] - mr);
            st[k2 * 68 + row] = e;
            s += e;
        }
        reds[row * 4 + part] = s;
        __syncthreads();
        if (part == 0) {
            float l = reds[row * 4] + reds[row * 4 + 1] + reds[row * 4 + 2] + reds[row * 4 + 3];
            rowinv[row] = 1.0f / l;
        }
    }
    __syncthreads();

    // ---- Phase 3: O = P V, gate, store ----
    {
        const int a2 = tid >> 3;   // qi pair: 2*a2, 2*a2+1
        const int b2 = tid & 7;    // d group: 4*b2..
        float o0[4] = {0.f, 0.f, 0.f, 0.f};
        float o1[4] = {0.f, 0.f, 0.f, 0.f};
        for (int k2 = 0; k2 < 256; ++k2) {
            float2 pp = *(const float2*)&st[k2 * 68 + 2 * a2];
            float4 vv = *(const float4*)&vl[k2 * 32 + 4 * b2];
            float vs[4] = {vv.x, vv.y, vv.z, vv.w};
#pragma unroll
            for (int j = 0; j < 4; ++j) {
                o0[j] = fmaf(pp.x, vs[j], o0[j]);
                o1[j] = fmaf(pp.y, vs[j], o1[j]);
            }
        }
#pragma unroll
        for (int i = 0; i < 2; ++i) {
            int qi = 2 * a2 + i;
            int qg = qc * 64 + qi;
            float inv = rowinv[qi];
            size_t rowbase = ((size_t)(n * 256 + qg)) * 128 + h * 32 + 4 * b2;
            const float* oo = i ? o1 : o0;
#pragma unroll
            for (int j = 0; j < 4; ++j) {
                float g = bf2f(g_ws[rowbase + j]);
                o_ws[rowbase + j] = f2bf(oo[j] * inv * g);
            }
        }
    }
}

// =====================================================================
// Kernel 3: out = o_ws[65536x128](bf16) @ Wo[128x128] -> fp32
// =====================================================================
__global__ __launch_bounds__(256, 1) void outproj_kernel(
    const unsigned short* __restrict__ o_ws, const float* __restrict__ Wo,
    float* __restrict__ out)
{
    __shared__ float Wl[128 * 128];
    __shared__ float Xl[128 * 68];

    const int tid = threadIdx.x;
    for (int i = tid; i < 128 * 128 / 4; i += 256) {
        ((float4*)Wl)[i] = ((const float4*)Wo)[i];
    }
    const int r0 = blockIdx.x * 64;
    for (int idx = tid; idx < 64 * 16; idx += 256) {
        int row = idx >> 4;
        int u = idx & 15;   // 8 bf16 per uint4
        uint4 raw = ((const uint4*)(o_ws + (size_t)(r0 + row) * 128))[u];
        unsigned int w[4] = {raw.x, raw.y, raw.z, raw.w};
#pragma unroll
        for (int t = 0; t < 4; ++t) {
            Xl[(u * 8 + 2 * t + 0) * 68 + row] = bf2f((unsigned short)(w[t] & 0xffff));
            Xl[(u * 8 + 2 * t + 1) * 68 + row] = bf2f((unsigned short)(w[t] >> 16));
        }
    }
    __syncthreads();

    const int ti = tid & 15;
    const int tj = tid >> 4;
    float acc[4][8];
#pragma unroll
    for (int i = 0; i < 4; ++i)
#pragma unroll
        for (int j = 0; j < 8; ++j) acc[i][j] = 0.f;

    for (int k = 0; k < 128; ++k) {
        float4 xv = *(const float4*)&Xl[k * 68 + 4 * tj];
        float4 w0 = *(const float4*)&Wl[k * 128 + 8 * ti];
        float4 w1 = *(const float4*)&Wl[k * 128 + 8 * ti + 4];
        float xs[4] = {xv.x, xv.y, xv.z, xv.w};
        float ws[8] = {w0.x, w0.y, w0.z, w0.w, w1.x, w1.y, w1.z, w1.w};
#pragma unroll
        for (int i = 0; i < 4; ++i)
#pragma unroll
            for (int j = 0; j < 8; ++j) acc[i][j] = fmaf(xs[i], ws[j], acc[i][j]);
    }

#pragma unroll
    for (int i = 0; i < 4; ++i) {
        size_t r = r0 + 4 * tj + i;
        float4 a0 = make_float4(acc[i][0], acc[i][1], acc[i][2], acc[i][3]);
        float4 a1 = make_float4(acc[i][4], acc[i][5], acc[i][6], acc[i][7]);
        *(float4*)(out + r * 128 + 8 * ti) = a0;
        *(float4*)(out + r * 128 + 8 * ti + 4) = a1;
    }
}

// =====================================================================
extern "C" void kernel_launch(void* const* d_in, const int* in_sizes, int n_in,
                              void* d_out, int out_size, void* d_ws, size_t ws_size,
                              hipStream_t stream) {
    const float* qx  = (const float*)d_in[0];
    const float* kvx = (const float*)d_in[1];
    const float* tri = (const float*)d_in[2];
    const float* mb  = (const float*)d_in[3];
    // d_in[4] = mask (unused: mask_bias carries it in the reference path)
    const float* Wq  = (const float*)d_in[5];
    const float* Wk  = (const float*)d_in[6];
    const float* Wv  = (const float*)d_in[7];
    const float* Wg  = (const float*)d_in[8];
    const float* Wo  = (const float*)d_in[9];
    float* out = (float*)d_out;

    unsigned short* ws = (unsigned short*)d_ws;
    const size_t RC = (size_t)RROWS * 128;
    unsigned short* q_ws = ws;            // [n][h][q][32]
    unsigned short* k_ws = ws + RC;       // [n][h][k][32]
    unsigned short* v_ws = ws + 2 * RC;   // [n][h][k][32]
    unsigned short* g_ws = ws + 3 * RC;   // [n][q][128]
    unsigned short* o_ws = ws + 4 * RC;   // [n][q][128]

    proj_kernel<<<dim3(RROWS / 64, 4), 256, 0, stream>>>(
        qx, kvx, Wq, Wk, Wv, Wg, q_ws, k_ws, v_ws, g_ws);
    attn_kernel<<<dim3(4, NDIM, HH), 256, 0, stream>>>(
        q_ws, k_ws, v_ws, g_ws, tri, mb, o_ws);
    outproj_kernel<<<dim3(RROWS / 64), 256, 0, stream>>>(o_ws, Wo, out);
}

// Round 2
// 535.474 us; speedup vs baseline: 1.6346x; 1.6346x over previous
//
#include <hip/hip_runtime.h>
#include <hip/hip_bf16.h>

// Problem constants
#define NDIM 256   // outer n
#define QDIM 256   // q/k sequence
#define CDIM 128   // channels
#define HH 4       // heads
#define DD 32      // head dim
#define RROWS (NDIM * QDIM)  // 65536 flattened rows

// ---------- bf16 helpers (raw ushort storage, fp32 compute) ----------
__device__ __forceinline__ float bf2f(unsigned short u) {
    unsigned int x = ((unsigned int)u) << 16;
    return __uint_as_float(x);
}
__device__ __forceinline__ unsigned short f2bf(float f) {
    unsigned int x = __float_as_uint(f);
    unsigned int lsb = (x >> 16) & 1u;
    x += 0x7fffu + lsb;   // round-to-nearest-even
    return (unsigned short)(x >> 16);
}

// MFMA fragment types (gfx950: mfma_f32_16x16x32_bf16)
typedef __bf16 bf16x8v __attribute__((ext_vector_type(8)));
typedef float  f32x4v  __attribute__((ext_vector_type(4)));
union frag_u { uint4 u; bf16x8v v; };

// =====================================================================
// Kernel 1: projections (unchanged from round 0).
// =====================================================================
__global__ __launch_bounds__(256, 1) void proj_kernel(
    const float* __restrict__ qx, const float* __restrict__ kvx,
    const float* __restrict__ Wq, const float* __restrict__ Wk,
    const float* __restrict__ Wv, const float* __restrict__ Wg,
    unsigned short* __restrict__ q_ws, unsigned short* __restrict__ k_ws,
    unsigned short* __restrict__ v_ws, unsigned short* __restrict__ g_ws)
{
    __shared__ float Wl[128 * 128];   // [k][c]  64 KB
    __shared__ float Xl[128 * 68];    // [k][row] padded, 34 KB

    const int tid = threadIdx.x;
    const int p = blockIdx.y;
    const float* __restrict__ X = (p == 0 || p == 3) ? qx : kvx;
    const float* __restrict__ W = (p == 0) ? Wq : (p == 1) ? Wk : (p == 2) ? Wv : Wg;

    for (int i = tid; i < 128 * 128 / 4; i += 256) {
        ((float4*)Wl)[i] = ((const float4*)W)[i];
    }
    const int r0 = blockIdx.x * 64;
    for (int idx = tid; idx < 64 * 32; idx += 256) {
        int row = idx >> 5;
        int c4 = idx & 31;
        float4 xv = ((const float4*)(X + (size_t)(r0 + row) * 128))[c4];
        Xl[(c4 * 4 + 0) * 68 + row] = xv.x;
        Xl[(c4 * 4 + 1) * 68 + row] = xv.y;
        Xl[(c4 * 4 + 2) * 68 + row] = xv.z;
        Xl[(c4 * 4 + 3) * 68 + row] = xv.w;
    }
    __syncthreads();

    const int ti = tid & 15;
    const int tj = tid >> 4;

    float acc[4][8];
#pragma unroll
    for (int i = 0; i < 4; ++i)
#pragma unroll
        for (int j = 0; j < 8; ++j) acc[i][j] = 0.f;

    for (int k = 0; k < 128; ++k) {
        float4 xv = *(const float4*)&Xl[k * 68 + 4 * tj];
        float4 w0 = *(const float4*)&Wl[k * 128 + 8 * ti];
        float4 w1 = *(const float4*)&Wl[k * 128 + 8 * ti + 4];
        float xs[4] = {xv.x, xv.y, xv.z, xv.w};
        float ws[8] = {w0.x, w0.y, w0.z, w0.w, w1.x, w1.y, w1.z, w1.w};
#pragma unroll
        for (int i = 0; i < 4; ++i)
#pragma unroll
            for (int j = 0; j < 8; ++j) acc[i][j] = fmaf(xs[i], ws[j], acc[i][j]);
    }

#pragma unroll
    for (int i = 0; i < 4; ++i) {
        int r = r0 + 4 * tj + i;
        int n = r >> 8;
        int si = r & 255;
#pragma unroll
        for (int j = 0; j < 8; ++j) {
            int c = 8 * ti + j;
            float v = acc[i][j];
            if (p == 0) {
                v *= 0.17677669529663687f;  // 1/sqrt(32)
                int h = c >> 5, d = c & 31;
                q_ws[((size_t)(n * HH + h) * QDIM + si) * DD + d] = f2bf(v);
            } else if (p == 1) {
                int h = c >> 5, d = c & 31;
                k_ws[((size_t)(n * HH + h) * QDIM + si) * DD + d] = f2bf(v);
            } else if (p == 2) {
                int h = c >> 5, d = c & 31;
                v_ws[((size_t)(n * HH + h) * QDIM + si) * DD + d] = f2bf(v);
            } else {
                float s = 1.0f / (1.0f + __expf(-v));
                g_ws[(size_t)r * 128 + c] = f2bf(s);
            }
        }
    }
}

// =====================================================================
// Kernel 2: MFMA attention. Block = 256 thr (4 waves), grid (4 qc, n, h).
// Wave w owns 16 queries. S^T = K*q^T via mfma_f32_16x16x32_bf16
// (A = K frags, B = q frags, straight from global: 16B/lane coalesced).
// Softmax over keys = per-lane reduce over 16 C-frags + shfl_xor(16,32).
// P packed to LDS (b64 writes, 264-bf16 row pad), PV via ds_read_b128
// A/B frags with V^T staged once in LDS. One __syncthreads total.
// =====================================================================
__global__ __launch_bounds__(256, 3) void attn_kernel(
    const unsigned short* __restrict__ q_ws, const unsigned short* __restrict__ k_ws,
    const unsigned short* __restrict__ v_ws, const unsigned short* __restrict__ g_ws,
    const float* __restrict__ tri, const float* __restrict__ mb,
    unsigned short* __restrict__ o_ws)
{
    __shared__ unsigned short vl[32 * 264];   // V^T [d][key], 16.9 KB
    __shared__ unsigned short Pl[64 * 264];   // P [q][key],   33.8 KB
    __shared__ float sinv[4][16];             // per-wave 1/rowsum

    const int tid = threadIdx.x;
    const int qc = blockIdx.x;   // 0..3 (64-query chunk)
    const int n  = blockIdx.y;
    const int h  = blockIdx.z;
    const size_t base = (size_t)(n * HH + h) * QDIM * DD;

    // ---- Stage V^T into LDS (coalesced uint4 reads, u16 transpose writes)
    for (int t = 0; t < 4; ++t) {
        int idx = tid + t * 256;        // 0..1023
        int key = idx >> 2;             // 0..255
        int u = idx & 3;                // 8-bf16 group within row
        union { uint4 q; unsigned short s[8]; } raw;
        raw.q = *(const uint4*)(v_ws + base + (size_t)key * DD + u * 8);
#pragma unroll
        for (int j = 0; j < 8; ++j)
            vl[(u * 8 + j) * 264 + key] = raw.s[j];
    }

    const int wv   = tid >> 6;   // wave 0..3
    const int lane = tid & 63;
    const int col  = lane & 15;
    const int quad = lane >> 4;
    const int qg   = qc * 64 + wv * 16 + col;   // this lane's query (as B col)

    // ---- B frag: q[query=col][d = quad*8 + 0..7]
    frag_u bq;
    bq.u = *(const uint4*)(q_ws + base + (size_t)qg * DD + quad * 8);

    // ---- S^T tiles: 16 m-tiles of keys, C init = biases
    f32x4v acc[16];
#pragma unroll
    for (int mt = 0; mt < 16; ++mt) {
        int k0 = mt * 16 + quad * 4;   // this lane's 4 keys (C rows)
        float4 t4 = *(const float4*)&tri[((size_t)(h * 256 + qg)) * 256 + k0];
        float4 m4 = *(const float4*)&mb[n * 256 + k0];
        f32x4v c;
        c[0] = t4.x + m4.x; c[1] = t4.y + m4.y;
        c[2] = t4.z + m4.z; c[3] = t4.w + m4.w;
        frag_u ak;
        ak.u = *(const uint4*)(k_ws + base + (size_t)(mt * 16 + col) * DD + quad * 8);
        acc[mt] = __builtin_amdgcn_mfma_f32_16x16x32_bf16(ak.v, bq.v, c, 0, 0, 0);
    }

    // ---- softmax over keys (rows of S^T): per-lane 64 vals + cross-quad
    float mx = -1e30f;
#pragma unroll
    for (int mt = 0; mt < 16; ++mt)
#pragma unroll
        for (int r = 0; r < 4; ++r) mx = fmaxf(mx, acc[mt][r]);
    mx = fmaxf(mx, __shfl_xor(mx, 16));
    mx = fmaxf(mx, __shfl_xor(mx, 32));

    float sum = 0.f;
#pragma unroll
    for (int mt = 0; mt < 16; ++mt)
#pragma unroll
        for (int r = 0; r < 4; ++r) {
            float e = __expf(acc[mt][r] - mx);
            acc[mt][r] = e;
            sum += e;
        }
    sum += __shfl_xor(sum, 16);
    sum += __shfl_xor(sum, 32);
    if (quad == 0) sinv[wv][col] = 1.0f / sum;

    // ---- pack P to LDS: row = query (w*16+col), 4 consecutive keys per b64
#pragma unroll
    for (int mt = 0; mt < 16; ++mt) {
        ushort4 pk;
        pk.x = f2bf(acc[mt][0]); pk.y = f2bf(acc[mt][1]);
        pk.z = f2bf(acc[mt][2]); pk.w = f2bf(acc[mt][3]);
        *(ushort4*)&Pl[(wv * 16 + col) * 264 + mt * 16 + quad * 4] = pk;
    }

    __syncthreads();   // covers vl (cross-wave), Pl & sinv (intra-wave)

    // ---- O = P V : M=16 (wave queries), N=32 (d, 2 tiles), K=256 (8 steps)
    f32x4v o0 = {0.f, 0.f, 0.f, 0.f};
    f32x4v o1 = {0.f, 0.f, 0.f, 0.f};
#pragma unroll
    for (int kc = 0; kc < 8; ++kc) {
        frag_u ap, b0, b1;
        ap.u = *(const uint4*)&Pl[(wv * 16 + col) * 264 + kc * 32 + quad * 8];
        b0.u = *(const uint4*)&vl[(col) * 264 + kc * 32 + quad * 8];
        b1.u = *(const uint4*)&vl[(16 + col) * 264 + kc * 32 + quad * 8];
        o0 = __builtin_amdgcn_mfma_f32_16x16x32_bf16(ap.v, b0.v, o0, 0, 0, 0);
        o1 = __builtin_amdgcn_mfma_f32_16x16x32_bf16(ap.v, b1.v, o1, 0, 0, 0);
    }

    // ---- epilogue: normalize, gate, store bf16
#pragma unroll
    for (int r = 0; r < 4; ++r) {
        int qi = quad * 4 + r;                     // query within wave tile
        int qglob = qc * 64 + wv * 16 + qi;
        float iv = sinv[wv][qi];
        size_t ob = ((size_t)(n * 256 + qglob)) * 128 + h * 32;
        float g0 = bf2f(g_ws[ob + col]);
        o_ws[ob + col] = f2bf(o0[r] * iv * g0);
        float g1 = bf2f(g_ws[ob + 16 + col]);
        o_ws[ob + 16 + col] = f2bf(o1[r] * iv * g1);
    }
}

// =====================================================================
// Kernel 3: out = o_ws[65536x128](bf16) @ Wo[128x128] -> fp32 (unchanged)
// =====================================================================
__global__ __launch_bounds__(256, 1) void outproj_kernel(
    const unsigned short* __restrict__ o_ws, const float* __restrict__ Wo,
    float* __restrict__ out)
{
    __shared__ float Wl[128 * 128];
    __shared__ float Xl[128 * 68];

    const int tid = threadIdx.x;
    for (int i = tid; i < 128 * 128 / 4; i += 256) {
        ((float4*)Wl)[i] = ((const float4*)Wo)[i];
    }
    const int r0 = blockIdx.x * 64;
    for (int idx = tid; idx < 64 * 16; idx += 256) {
        int row = idx >> 4;
        int u = idx & 15;
        uint4 raw = ((const uint4*)(o_ws + (size_t)(r0 + row) * 128))[u];
        unsigned int w[4] = {raw.x, raw.y, raw.z, raw.w};
#pragma unroll
        for (int t = 0; t < 4; ++t) {
            Xl[(u * 8 + 2 * t + 0) * 68 + row] = bf2f((unsigned short)(w[t] & 0xffff));
            Xl[(u * 8 + 2 * t + 1) * 68 + row] = bf2f((unsigned short)(w[t] >> 16));
        }
    }
    __syncthreads();

    const int ti = tid & 15;
    const int tj = tid >> 4;
    float acc[4][8];
#pragma unroll
    for (int i = 0; i < 4; ++i)
#pragma unroll
        for (int j = 0; j < 8; ++j) acc[i][j] = 0.f;

    for (int k = 0; k < 128; ++k) {
        float4 xv = *(const float4*)&Xl[k * 68 + 4 * tj];
        float4 w0 = *(const float4*)&Wl[k * 128 + 8 * ti];
        float4 w1 = *(const float4*)&Wl[k * 128 + 8 * ti + 4];
        float xs[4] = {xv.x, xv.y, xv.z, xv.w};
        float ws[8] = {w0.x, w0.y, w0.z, w0.w, w1.x, w1.y, w1.z, w1.w};
#pragma unroll
        for (int i = 0; i < 4; ++i)
#pragma unroll
            for (int j = 0; j < 8; ++j) acc[i][j] = fmaf(xs[i], ws[j], acc[i][j]);
    }

#pragma unroll
    for (int i = 0; i < 4; ++i) {
        size_t r = r0 + 4 * tj + i;
        float4 a0 = make_float4(acc[i][0], acc[i][1], acc[i][2], acc[i][3]);
        float4 a1 = make_float4(acc[i][4], acc[i][5], acc[i][6], acc[i][7]);
        *(float4*)(out + r * 128 + 8 * ti) = a0;
        *(float4*)(out + r * 128 + 8 * ti + 4) = a1;
    }
}

// =====================================================================
extern "C" void kernel_launch(void* const* d_in, const int* in_sizes, int n_in,
                              void* d_out, int out_size, void* d_ws, size_t ws_size,
                              hipStream_t stream) {
    const float* qx  = (const float*)d_in[0];
    const float* kvx = (const float*)d_in[1];
    const float* tri = (const float*)d_in[2];
    const float* mb  = (const float*)d_in[3];
    // d_in[4] = mask (unused: mask_bias carries it in the reference path)
    const float* Wq  = (const float*)d_in[5];
    const float* Wk  = (const float*)d_in[6];
    const float* Wv  = (const float*)d_in[7];
    const float* Wg  = (const float*)d_in[8];
    const float* Wo  = (const float*)d_in[9];
    float* out = (float*)d_out;

    unsigned short* ws = (unsigned short*)d_ws;
    const size_t RC = (size_t)RROWS * 128;
    unsigned short* q_ws = ws;            // [n][h][q][32]
    unsigned short* k_ws = ws + RC;       // [n][h][k][32]
    unsigned short* v_ws = ws + 2 * RC;   // [n][h][k][32]
    unsigned short* g_ws = ws + 3 * RC;   // [n][q][128]
    unsigned short* o_ws = ws + 4 * RC;   // [n][q][128]

    proj_kernel<<<dim3(RROWS / 64, 4), 256, 0, stream>>>(
        qx, kvx, Wq, Wk, Wv, Wg, q_ws, k_ws, v_ws, g_ws);
    attn_kernel<<<dim3(4, NDIM, HH), 256, 0, stream>>>(
        q_ws, k_ws, v_ws, g_ws, tri, mb, o_ws);
    outproj_kernel<<<dim3(RROWS / 64), 256, 0, stream>>>(o_ws, Wo, out);
}

// Round 3
// 275.652 us; speedup vs baseline: 3.1752x; 1.9426x over previous
//
#include <hip/hip_runtime.h>
#include <hip/hip_bf16.h>

// Problem constants
#define NDIM 256   // outer n
#define QDIM 256   // q/k sequence
#define CDIM 128   // channels
#define HH 4       // heads
#define DD 32      // head dim
#define RROWS (NDIM * QDIM)  // 65536 flattened rows

// ---------- bf16 helpers (raw ushort storage, fp32 compute) ----------
__device__ __forceinline__ float bf2f(unsigned short u) {
    unsigned int x = ((unsigned int)u) << 16;
    return __uint_as_float(x);
}
__device__ __forceinline__ unsigned short f2bf(float f) {
    unsigned int x = __float_as_uint(f);
    unsigned int lsb = (x >> 16) & 1u;
    x += 0x7fffu + lsb;   // round-to-nearest-even
    return (unsigned short)(x >> 16);
}

// MFMA fragment types (gfx950: mfma_f32_16x16x32_bf16)
typedef __bf16 bf16x8v __attribute__((ext_vector_type(8)));
typedef float  f32x4v  __attribute__((ext_vector_type(4)));
union frag_u { uint4 u; bf16x8v v; };

__device__ __forceinline__ bf16x8v cvt8(float4 f0, float4 f1) {
    bf16x8v r;
    r[0] = (__bf16)f0.x; r[1] = (__bf16)f0.y; r[2] = (__bf16)f0.z; r[3] = (__bf16)f0.w;
    r[4] = (__bf16)f1.x; r[5] = (__bf16)f1.y; r[6] = (__bf16)f1.z; r[7] = (__bf16)f1.w;
    return r;
}

// =====================================================================
// Kernel 0: weight prep. One block per matrix (5 blocks).
// wt[p][n][k] = bf16(W_p[k][n])   (transposed so B-frags are contiguous)
// =====================================================================
__global__ __launch_bounds__(256, 1) void prep_weights(
    const float* __restrict__ Wq, const float* __restrict__ Wk,
    const float* __restrict__ Wv, const float* __restrict__ Wg,
    const float* __restrict__ Wo, unsigned short* __restrict__ wt)
{
    __shared__ unsigned short t[128][136];
    const int p = blockIdx.x;
    const float* __restrict__ W = (p == 0) ? Wq : (p == 1) ? Wk :
                                  (p == 2) ? Wv : (p == 3) ? Wg : Wo;
    const int tid = threadIdx.x;
    for (int idx = tid; idx < 16384; idx += 256) {
        int k = idx >> 7, n = idx & 127;
        t[k][n] = f2bf(W[idx]);
    }
    __syncthreads();
    unsigned short* dst = wt + (size_t)p * 16384;
    for (int idx = tid; idx < 16384; idx += 256) {
        int n = idx >> 7, k = idx & 127;
        dst[idx] = t[k][n];   // Wt[n][k] = W[k][n]
    }
}

// =====================================================================
// Kernel 1: fused MFMA projections. grid (RROWS/128, 2), 256 thr.
//   pp=0: X=qx  -> q (scaled) and g (sigmoid)
//   pp=1: X=kvx -> k and v
// No LDS, no syncthreads. A-frags from global fp32 (cvt in-reg),
// B-frags from bf16 Wt (cache-resident). 32 acc frags per wave.
// =====================================================================
__global__ __launch_bounds__(256, 2) void proj_mfma(
    const float* __restrict__ qx, const float* __restrict__ kvx,
    const unsigned short* __restrict__ wt,
    unsigned short* __restrict__ q_ws, unsigned short* __restrict__ k_ws,
    unsigned short* __restrict__ v_ws, unsigned short* __restrict__ g_ws)
{
    const int tid = threadIdx.x;
    const int pp = blockIdx.y;
    const float* __restrict__ X = pp ? kvx : qx;
    // pp=0: A-path = Wq (idx 0), B-path = Wg (idx 3)
    // pp=1: A-path = Wk (idx 1), B-path = Wv (idx 2)
    const unsigned short* __restrict__ WtA = wt + (size_t)(pp ? 1 : 0) * 16384;
    const unsigned short* __restrict__ WtB = wt + (size_t)(pp ? 2 : 3) * 16384;

    const int wv   = tid >> 6;
    const int lane = tid & 63;
    const int col  = lane & 15;
    const int quad = lane >> 4;
    const int r0   = blockIdx.x * 128 + wv * 32;   // this wave's 32 rows

    f32x4v accA[2][8], accB[2][8];
#pragma unroll
    for (int mt = 0; mt < 2; ++mt)
#pragma unroll
        for (int nt = 0; nt < 8; ++nt) {
            accA[mt][nt] = (f32x4v){0.f, 0.f, 0.f, 0.f};
            accB[mt][nt] = (f32x4v){0.f, 0.f, 0.f, 0.f};
        }

#pragma unroll
    for (int kt = 0; kt < 4; ++kt) {
        frag_u a[2];
#pragma unroll
        for (int mt = 0; mt < 2; ++mt) {
            const float* src = X + (size_t)(r0 + mt * 16 + col) * 128 + kt * 32 + quad * 8;
            float4 f0 = *(const float4*)src;
            float4 f1 = *(const float4*)(src + 4);
            a[mt].v = cvt8(f0, f1);
        }
#pragma unroll
        for (int nt = 0; nt < 8; ++nt) {
            frag_u b0, b1;
            b0.u = *(const uint4*)(WtA + (size_t)(nt * 16 + col) * 128 + kt * 32 + quad * 8);
            b1.u = *(const uint4*)(WtB + (size_t)(nt * 16 + col) * 128 + kt * 32 + quad * 8);
            accA[0][nt] = __builtin_amdgcn_mfma_f32_16x16x32_bf16(a[0].v, b0.v, accA[0][nt], 0, 0, 0);
            accA[1][nt] = __builtin_amdgcn_mfma_f32_16x16x32_bf16(a[1].v, b0.v, accA[1][nt], 0, 0, 0);
            accB[0][nt] = __builtin_amdgcn_mfma_f32_16x16x32_bf16(a[0].v, b1.v, accB[0][nt], 0, 0, 0);
            accB[1][nt] = __builtin_amdgcn_mfma_f32_16x16x32_bf16(a[1].v, b1.v, accB[1][nt], 0, 0, 0);
        }
    }

    // epilogue: C row m = mt*16 + quad*4 + r; col n = nt*16 + col
#pragma unroll
    for (int mt = 0; mt < 2; ++mt) {
#pragma unroll
        for (int r = 0; r < 4; ++r) {
            int row = r0 + mt * 16 + quad * 4 + r;
            int n = row >> 8;
            int si = row & 255;
#pragma unroll
            for (int nt = 0; nt < 8; ++nt) {
                int c = nt * 16 + col;
                int h = c >> 5, d = c & 31;
                if (pp == 0) {
                    float qv = accA[mt][nt][r] * 0.17677669529663687f;  // 1/sqrt(32)
                    q_ws[((size_t)(n * HH + h) * QDIM + si) * DD + d] = f2bf(qv);
                    float s = 1.0f / (1.0f + __expf(-accB[mt][nt][r]));
                    g_ws[(size_t)row * 128 + c] = f2bf(s);
                } else {
                    k_ws[((size_t)(n * HH + h) * QDIM + si) * DD + d] = f2bf(accA[mt][nt][r]);
                    v_ws[((size_t)(n * HH + h) * QDIM + si) * DD + d] = f2bf(accB[mt][nt][r]);
                }
            }
        }
    }
}

// =====================================================================
// Kernel 2: MFMA attention (unchanged from round 1).
// =====================================================================
__global__ __launch_bounds__(256, 3) void attn_kernel(
    const unsigned short* __restrict__ q_ws, const unsigned short* __restrict__ k_ws,
    const unsigned short* __restrict__ v_ws, const unsigned short* __restrict__ g_ws,
    const float* __restrict__ tri, const float* __restrict__ mb,
    unsigned short* __restrict__ o_ws)
{
    __shared__ unsigned short vl[32 * 264];   // V^T [d][key], 16.9 KB
    __shared__ unsigned short Pl[64 * 264];   // P [q][key],   33.8 KB
    __shared__ float sinv[4][16];             // per-wave 1/rowsum

    const int tid = threadIdx.x;
    const int qc = blockIdx.x;   // 0..3 (64-query chunk)
    const int n  = blockIdx.y;
    const int h  = blockIdx.z;
    const size_t base = (size_t)(n * HH + h) * QDIM * DD;

    // ---- Stage V^T into LDS
    for (int t = 0; t < 4; ++t) {
        int idx = tid + t * 256;
        int key = idx >> 2;
        int u = idx & 3;
        union { uint4 q; unsigned short s[8]; } raw;
        raw.q = *(const uint4*)(v_ws + base + (size_t)key * DD + u * 8);
#pragma unroll
        for (int j = 0; j < 8; ++j)
            vl[(u * 8 + j) * 264 + key] = raw.s[j];
    }

    const int wv   = tid >> 6;
    const int lane = tid & 63;
    const int col  = lane & 15;
    const int quad = lane >> 4;
    const int qg   = qc * 64 + wv * 16 + col;

    frag_u bq;
    bq.u = *(const uint4*)(q_ws + base + (size_t)qg * DD + quad * 8);

    f32x4v acc[16];
#pragma unroll
    for (int mt = 0; mt < 16; ++mt) {
        int k0 = mt * 16 + quad * 4;
        float4 t4 = *(const float4*)&tri[((size_t)(h * 256 + qg)) * 256 + k0];
        float4 m4 = *(const float4*)&mb[n * 256 + k0];
        f32x4v c;
        c[0] = t4.x + m4.x; c[1] = t4.y + m4.y;
        c[2] = t4.z + m4.z; c[3] = t4.w + m4.w;
        frag_u ak;
        ak.u = *(const uint4*)(k_ws + base + (size_t)(mt * 16 + col) * DD + quad * 8);
        acc[mt] = __builtin_amdgcn_mfma_f32_16x16x32_bf16(ak.v, bq.v, c, 0, 0, 0);
    }

    float mx = -1e30f;
#pragma unroll
    for (int mt = 0; mt < 16; ++mt)
#pragma unroll
        for (int r = 0; r < 4; ++r) mx = fmaxf(mx, acc[mt][r]);
    mx = fmaxf(mx, __shfl_xor(mx, 16));
    mx = fmaxf(mx, __shfl_xor(mx, 32));

    float sum = 0.f;
#pragma unroll
    for (int mt = 0; mt < 16; ++mt)
#pragma unroll
        for (int r = 0; r < 4; ++r) {
            float e = __expf(acc[mt][r] - mx);
            acc[mt][r] = e;
            sum += e;
        }
    sum += __shfl_xor(sum, 16);
    sum += __shfl_xor(sum, 32);
    if (quad == 0) sinv[wv][col] = 1.0f / sum;

#pragma unroll
    for (int mt = 0; mt < 16; ++mt) {
        ushort4 pk;
        pk.x = f2bf(acc[mt][0]); pk.y = f2bf(acc[mt][1]);
        pk.z = f2bf(acc[mt][2]); pk.w = f2bf(acc[mt][3]);
        *(ushort4*)&Pl[(wv * 16 + col) * 264 + mt * 16 + quad * 4] = pk;
    }

    __syncthreads();

    f32x4v o0 = {0.f, 0.f, 0.f, 0.f};
    f32x4v o1 = {0.f, 0.f, 0.f, 0.f};
#pragma unroll
    for (int kc = 0; kc < 8; ++kc) {
        frag_u ap, b0, b1;
        ap.u = *(const uint4*)&Pl[(wv * 16 + col) * 264 + kc * 32 + quad * 8];
        b0.u = *(const uint4*)&vl[(col) * 264 + kc * 32 + quad * 8];
        b1.u = *(const uint4*)&vl[(16 + col) * 264 + kc * 32 + quad * 8];
        o0 = __builtin_amdgcn_mfma_f32_16x16x32_bf16(ap.v, b0.v, o0, 0, 0, 0);
        o1 = __builtin_amdgcn_mfma_f32_16x16x32_bf16(ap.v, b1.v, o1, 0, 0, 0);
    }

#pragma unroll
    for (int r = 0; r < 4; ++r) {
        int qi = quad * 4 + r;
        int qglob = qc * 64 + wv * 16 + qi;
        float iv = sinv[wv][qi];
        size_t ob = ((size_t)(n * 256 + qglob)) * 128 + h * 32;
        float g0 = bf2f(g_ws[ob + col]);
        o_ws[ob + col] = f2bf(o0[r] * iv * g0);
        float g1 = bf2f(g_ws[ob + 16 + col]);
        o_ws[ob + 16 + col] = f2bf(o1[r] * iv * g1);
    }
}

// =====================================================================
// Kernel 3: MFMA out-projection. grid RROWS/128, 256 thr, no LDS.
// out[65536x128] fp32 = o_ws(bf16) @ Wo  (B-frags from wt[4])
// =====================================================================
__global__ __launch_bounds__(256, 4) void outproj_mfma(
    const unsigned short* __restrict__ o_ws, const unsigned short* __restrict__ wt,
    float* __restrict__ out)
{
    const int tid = threadIdx.x;
    const unsigned short* __restrict__ Wt = wt + 4 * 16384;

    const int wv   = tid >> 6;
    const int lane = tid & 63;
    const int col  = lane & 15;
    const int quad = lane >> 4;
    const int r0   = blockIdx.x * 128 + wv * 32;

    f32x4v acc[2][8];
#pragma unroll
    for (int mt = 0; mt < 2; ++mt)
#pragma unroll
        for (int nt = 0; nt < 8; ++nt)
            acc[mt][nt] = (f32x4v){0.f, 0.f, 0.f, 0.f};

#pragma unroll
    for (int kt = 0; kt < 4; ++kt) {
        frag_u a[2];
#pragma unroll
        for (int mt = 0; mt < 2; ++mt)
            a[mt].u = *(const uint4*)(o_ws + (size_t)(r0 + mt * 16 + col) * 128 + kt * 32 + quad * 8);
#pragma unroll
        for (int nt = 0; nt < 8; ++nt) {
            frag_u b;
            b.u = *(const uint4*)(Wt + (size_t)(nt * 16 + col) * 128 + kt * 32 + quad * 8);
            acc[0][nt] = __builtin_amdgcn_mfma_f32_16x16x32_bf16(a[0].v, b.v, acc[0][nt], 0, 0, 0);
            acc[1][nt] = __builtin_amdgcn_mfma_f32_16x16x32_bf16(a[1].v, b.v, acc[1][nt], 0, 0, 0);
        }
    }

#pragma unroll
    for (int mt = 0; mt < 2; ++mt)
#pragma unroll
        for (int r = 0; r < 4; ++r) {
            size_t row = r0 + mt * 16 + quad * 4 + r;
#pragma unroll
            for (int nt = 0; nt < 8; ++nt)
                out[row * 128 + nt * 16 + col] = acc[mt][nt][r];
        }
}

// =====================================================================
extern "C" void kernel_launch(void* const* d_in, const int* in_sizes, int n_in,
                              void* d_out, int out_size, void* d_ws, size_t ws_size,
                              hipStream_t stream) {
    const float* qx  = (const float*)d_in[0];
    const float* kvx = (const float*)d_in[1];
    const float* tri = (const float*)d_in[2];
    const float* mb  = (const float*)d_in[3];
    // d_in[4] = mask (unused: mask_bias carries it in the reference path)
    const float* Wq  = (const float*)d_in[5];
    const float* Wk  = (const float*)d_in[6];
    const float* Wv  = (const float*)d_in[7];
    const float* Wg  = (const float*)d_in[8];
    const float* Wo  = (const float*)d_in[9];
    float* out = (float*)d_out;

    unsigned short* ws = (unsigned short*)d_ws;
    const size_t RC = (size_t)RROWS * 128;
    unsigned short* q_ws = ws;            // [n][h][q][32]
    unsigned short* k_ws = ws + RC;       // [n][h][k][32]
    unsigned short* v_ws = ws + 2 * RC;   // [n][h][k][32]
    unsigned short* g_ws = ws + 3 * RC;   // [n][q][128]
    unsigned short* o_ws = ws + 4 * RC;   // [n][q][128]
    unsigned short* wt   = ws + 5 * RC;   // 5 x [128][128] bf16 transposed weights

    prep_weights<<<dim3(5), 256, 0, stream>>>(Wq, Wk, Wv, Wg, Wo, wt);
    proj_mfma<<<dim3(RROWS / 128, 2), 256, 0, stream>>>(
        qx, kvx, wt, q_ws, k_ws, v_ws, g_ws);
    attn_kernel<<<dim3(4, NDIM, HH), 256, 0, stream>>>(
        q_ws, k_ws, v_ws, g_ws, tri, mb, o_ws);
    outproj_mfma<<<dim3(RROWS / 128), 256, 0, stream>>>(o_ws, wt, out);
}